// Round 14
// baseline (1637.471 us; speedup 1.0000x reference)
//
#include <hip/hip_runtime.h>

#define NN 50000
#define EE 800000
#define GG 256
#define IND 32
#define HID 108
#define NL 4
#define PB 768   // persistent blocks for LDS-GEMM kernels (3 blocks/CU @ ~48 KB LDS)

__global__ void k_zero(int* deg) {
    int i = blockIdx.x * 256 + threadIdx.x;
    if (i < NN) deg[i] = 0;
}

__global__ void k_hist(const int* dst, int* deg) {
    int e = blockIdx.x * 256 + threadIdx.x;
    if (e < EE) atomicAdd(&deg[dst[e]], 1);
}

__global__ void k_scan(const int* deg, int* rp) {
    __shared__ int s[1024];
    __shared__ int carry;
    int tid = threadIdx.x;
    if (tid == 0) { carry = 0; rp[0] = 0; }
    __syncthreads();
    for (int base = 0; base < NN; base += 1024) {
        int i = base + tid;
        s[tid] = (i < NN) ? deg[i] : 0;
        __syncthreads();
        for (int off = 1; off < 1024; off <<= 1) {
            int t = (tid >= off) ? s[tid - off] : 0;
            __syncthreads();
            s[tid] += t;
            __syncthreads();
        }
        int cb = carry;
        __syncthreads();
        if (i < NN) rp[i + 1] = cb + s[tid];
        if (tid == 0) carry = cb + s[1023];
        __syncthreads();
    }
}

__global__ void k_scatter(const int* src, const int* dst, const int* rp,
                          int* deg, int* cs) {
    int e = blockIdx.x * 256 + threadIdx.x;
    if (e < EE) {
        int d = dst[e];
        int pos = atomicSub(&deg[d], 1) - 1;
        cs[rp[d] + pos] = src[e];
    }
}

__global__ void k_embed(const float* feat, const float* W,
                        const float* b, float* h) {
    int i = blockIdx.x * 256 + threadIdx.x;
    if (i >= NN * HID) return;
    int n = i / HID, c = i - n * HID;
    float acc = b[c];
    const float* fr = feat + (size_t)n * IND;
    for (int k = 0; k < IND; k++) acc += fr[k] * W[k * HID + c];
    h[i] = acc;
}

// out[n][c] = maybe_relu(b[c] + in[n][:] @ W[:HID][c]); W (108x108) staged in LDS.
__global__ __launch_bounds__(256)
void k_gemm_lds(const float* __restrict__ in, const float* __restrict__ W,
                const float* __restrict__ b, float* __restrict__ out, int relu) {
    __shared__ float Wl[HID * HID];
    __shared__ float hrow[2][HID];
    int tid = threadIdx.x;
    for (int i = tid; i < HID * HID; i += 256) Wl[i] = W[i];
    int r = tid / HID, c = tid - r * HID;    // valid for tid<216
    float bc = (tid < 216) ? b[c] : 0.f;
    for (int base = blockIdx.x * 2; base < NN; base += PB * 2) {
        __syncthreads();
        if (tid < 216) {
            int n = base + r;
            hrow[r][c] = (n < NN) ? in[(size_t)n * HID + c] : 0.f;
        }
        __syncthreads();
        if (tid < 216) {
            int n = base + r;
            if (n < NN) {
                float acc = bc;
                #pragma unroll 4
                for (int k = 0; k < HID; k++) acc += hrow[r][k] * Wl[k * HID + c];
                out[(size_t)n * HID + c] = relu ? fmaxf(acc, 0.f) : acc;
            }
        }
    }
}

// agg[n][:] = mean over in-neighbors of hp. 128 thr: 4 edge-slices x 27 float4 lanes.
__global__ __launch_bounds__(128)
void k_agg(const float* __restrict__ hp, const int* __restrict__ rp,
           const int* __restrict__ cs, float* __restrict__ agg) {
    __shared__ float asl[4][HID];
    int n = blockIdx.x, tid = threadIdx.x;
    int t = tid & 31, q = tid >> 5;
    int s0 = rp[n], s1 = rp[n + 1];
    if (t < 27) {
        float a0 = 0.f, a1 = 0.f, a2 = 0.f, a3 = 0.f;
        int coff = 4 * t;
        int e = s0 + q;
        for (; e + 4 < s1; e += 8) {
            const float4 v0 = *(const float4*)(hp + (size_t)cs[e] * HID + coff);
            const float4 v1 = *(const float4*)(hp + (size_t)cs[e + 4] * HID + coff);
            a0 += v0.x + v1.x; a1 += v0.y + v1.y;
            a2 += v0.z + v1.z; a3 += v0.w + v1.w;
        }
        if (e < s1) {
            const float4 v = *(const float4*)(hp + (size_t)cs[e] * HID + coff);
            a0 += v.x; a1 += v.y; a2 += v.z; a3 += v.w;
        }
        asl[q][coff] = a0; asl[q][coff + 1] = a1;
        asl[q][coff + 2] = a2; asl[q][coff + 3] = a3;
    }
    __syncthreads();
    if (tid < HID) {
        int dg = s1 - s0;
        float inv = 1.0f / (float)((dg > 1) ? dg : 1);
        agg[(size_t)n * HID + tid] =
            (asl[0][tid] + asl[1][tid] + asl[2][tid] + asl[3][tid]) * inv;
    }
}

// bu = part[n][c] + agg[n][:] @ W2[:][c]; h[n][c] += relu(l2norm_row(bu)).
// W2 (second 108 rows of W_app) staged in LDS.
__global__ __launch_bounds__(256)
void k_app2(const float* __restrict__ h, const float* __restrict__ agg,
            const float* __restrict__ part, const float* __restrict__ W2,
            float* __restrict__ hout) {
    __shared__ float Wl[HID * HID];
    __shared__ float arow[2][HID];
    __shared__ float red[2][128];
    int tid = threadIdx.x;
    for (int i = tid; i < HID * HID; i += 256) Wl[i] = W2[i];
    int r = tid / HID, c = tid - r * HID;    // valid for tid<216
    int r2 = tid >> 7, c2 = tid & 127;
    for (int base = blockIdx.x * 2; base < NN; base += PB * 2) {
        __syncthreads();
        red[r2][c2] = 0.f;
        if (tid < 216) {
            int n = base + r;
            arow[r][c] = (n < NN) ? agg[(size_t)n * HID + c] : 0.f;
        }
        __syncthreads();
        float bu = 0.f;
        int n = base + r;
        if (tid < 216 && n < NN) {
            bu = part[(size_t)n * HID + c];
            #pragma unroll 4
            for (int k = 0; k < HID; k++) bu += arow[r][k] * Wl[k * HID + c];
            red[r][c] = bu * bu;
        }
        __syncthreads();
        for (int off = 64; off > 0; off >>= 1) {
            if (c2 < off) red[r2][c2] += red[r2][c2 + off];
            __syncthreads();
        }
        if (tid < 216 && n < NN) {
            float inv = 1.0f / fmaxf(sqrtf(red[r][0]), 1e-12f);
            float v = fmaxf(bu * inv, 0.f);
            hout[(size_t)n * HID + c] = h[(size_t)n * HID + c] + v;
        }
    }
}

__global__ void k_readout(const float* h, const int* gid,
                          const float* W1, const float* b1,
                          const float* W2, const float* b2,
                          const float* W3, const float* b3,
                          float* out) {
    __shared__ float hg[HID];
    __shared__ float y1[54];
    __shared__ float y2[27];
    __shared__ int se[2];
    int g = blockIdx.x, tid = threadIdx.x;
    if (tid < 2) {
        int key = g + tid, lo = 0, hi = NN;
        while (lo < hi) {
            int mid = (lo + hi) >> 1;
            if (gid[mid] < key) lo = mid + 1; else hi = mid;
        }
        se[tid] = lo;
    }
    __syncthreads();
    int s = se[0], e = se[1];
    if (tid < HID) {
        float acc = 0.f;
        for (int n = s; n < e; n++) acc += h[(size_t)n * HID + tid];
        int cnt = e - s;
        hg[tid] = acc / (float)((cnt > 1) ? cnt : 1);
    }
    __syncthreads();
    if (tid < 54) {
        float a = b1[tid];
        for (int k = 0; k < HID; k++) a += hg[k] * W1[k * 54 + tid];
        y1[tid] = fmaxf(a, 0.f);
    }
    __syncthreads();
    if (tid < 27) {
        float a = b2[tid];
        for (int k = 0; k < 54; k++) a += y1[k] * W2[k * 27 + tid];
        y2[tid] = fmaxf(a, 0.f);
    }
    __syncthreads();
    if (tid < 10) {
        float a = b3[tid];
        for (int k = 0; k < 27; k++) a += y2[k] * W3[k * 10 + tid];
        out[g * 10 + tid] = a;
    }
}

extern "C" void kernel_launch(void* const* d_in, const int* in_sizes, int n_in,
                              void* d_out, int out_size, void* d_ws, size_t ws_size,
                              hipStream_t stream) {
    float* out = (float*)d_out;
    (void)in_sizes; (void)n_in; (void)ws_size; (void)out_size;

    const float* feat   = (const float*)d_in[0];
    const int*   src    = (const int*)d_in[4];
    const int*   dst    = (const int*)d_in[5];
    const int*   gid    = (const int*)d_in[6];
    const float* W_emb  = (const float*)d_in[7];
    const float* b_emb  = (const float*)d_in[8];
    const float* W_pool = (const float*)d_in[9];
    const float* b_pool = (const float*)d_in[10];
    const float* W_app  = (const float*)d_in[11];
    const float* b_app  = (const float*)d_in[12];
    const float* W1     = (const float*)d_in[13];
    const float* b1     = (const float*)d_in[14];
    const float* W2     = (const float*)d_in[15];
    const float* b2     = (const float*)d_in[16];
    const float* W3     = (const float*)d_in[17];
    const float* b3     = (const float*)d_in[18];

    char* ws = (char*)d_ws;
    size_t off = 0;
    float* h    = (float*)(ws + off); off += ((size_t)NN * HID * 4 + 255) & ~(size_t)255;
    float* hp   = (float*)(ws + off); off += ((size_t)NN * HID * 4 + 255) & ~(size_t)255;
    float* agg  = (float*)(ws + off); off += ((size_t)NN * HID * 4 + 255) & ~(size_t)255;
    float* part = (float*)(ws + off); off += ((size_t)NN * HID * 4 + 255) & ~(size_t)255;
    int* cs     = (int*)(ws + off);   off += ((size_t)EE * 4 + 255) & ~(size_t)255;
    int* deg    = (int*)(ws + off);   off += ((size_t)NN * 4 + 255) & ~(size_t)255;
    int* rp     = (int*)(ws + off);   off += ((size_t)(NN + 1) * 4 + 255) & ~(size_t)255;

    int eblk = (NN * HID + 255) / 256;

    hipLaunchKernelGGL(k_zero, dim3((NN + 255) / 256), dim3(256), 0, stream, deg);
    hipLaunchKernelGGL(k_hist, dim3((EE + 255) / 256), dim3(256), 0, stream, dst, deg);
    hipLaunchKernelGGL(k_scan, dim3(1), dim3(1024), 0, stream, deg, rp);
    hipLaunchKernelGGL(k_scatter, dim3((EE + 255) / 256), dim3(256), 0, stream,
                       src, dst, rp, deg, cs);

    hipLaunchKernelGGL(k_embed, dim3(eblk), dim3(256), 0, stream, feat, W_emb, b_emb, h);
    for (int l = 0; l < NL; l++) {
        const float* Wp = W_pool + (size_t)l * HID * HID;
        const float* Wa = W_app + (size_t)l * 2 * HID * HID;   // rows 0..107: self
        const float* Wa2 = Wa + (size_t)HID * HID;             // rows 108..215: agg
        hipLaunchKernelGGL(k_gemm_lds, dim3(PB), dim3(256), 0, stream,
                           h, Wp, b_pool + (size_t)l * HID, hp, 1);
        hipLaunchKernelGGL(k_agg, dim3(NN), dim3(128), 0, stream, hp, rp, cs, agg);
        hipLaunchKernelGGL(k_gemm_lds, dim3(PB), dim3(256), 0, stream,
                           h, Wa, b_app + (size_t)l * HID, part, 0);
        hipLaunchKernelGGL(k_app2, dim3(PB), dim3(256), 0, stream,
                           h, agg, part, Wa2, h);
    }
    hipLaunchKernelGGL(k_readout, dim3(GG), dim3(128), 0, stream,
                       h, gid, W1, b1, W2, b2, W3, b3, out);
}

// Round 15
// 760.570 us; speedup vs baseline: 2.1530x; 2.1530x over previous
//
#include <hip/hip_runtime.h>

#define NN 50000
#define EE 800000
#define GG 256
#define IND 32
#define HID 108
#define NL 4
#define MB 782            // ceil(50000/64) M-tiles
#define LDSK 136          // LDS B row stride in halves (272 B = 17*16, conflict-safe)

typedef __attribute__((ext_vector_type(8))) _Float16 f16x8;
typedef __attribute__((ext_vector_type(4))) float floatx4;

__global__ void k_zero(int* deg) {
    int i = blockIdx.x * 256 + threadIdx.x;
    if (i < NN) deg[i] = 0;
}

__global__ void k_hist(const int* dst, int* deg) {
    int e = blockIdx.x * 256 + threadIdx.x;
    if (e < EE) atomicAdd(&deg[dst[e]], 1);
}

__global__ void k_scan(const int* deg, int* rp) {
    __shared__ int s[1024];
    __shared__ int carry;
    int tid = threadIdx.x;
    if (tid == 0) { carry = 0; rp[0] = 0; }
    __syncthreads();
    for (int base = 0; base < NN; base += 1024) {
        int i = base + tid;
        s[tid] = (i < NN) ? deg[i] : 0;
        __syncthreads();
        for (int off = 1; off < 1024; off <<= 1) {
            int t = (tid >= off) ? s[tid - off] : 0;
            __syncthreads();
            s[tid] += t;
            __syncthreads();
        }
        int cb = carry;
        __syncthreads();
        if (i < NN) rp[i + 1] = cb + s[tid];
        if (tid == 0) carry = cb + s[1023];
        __syncthreads();
    }
}

__global__ void k_scatter(const int* src, const int* dst, const int* rp,
                          int* deg, int* cs) {
    int e = blockIdx.x * 256 + threadIdx.x;
    if (e < EE) {
        int d = dst[e];
        int pos = atomicSub(&deg[d], 1) - 1;
        cs[rp[d] + pos] = src[e];
    }
}

// Pack weights: fp16, transposed Bt[n][k], K padded to 128.
// Bt1[l][256][128]: n<108 -> W_pool[l][k][n]; 128<=n<236 -> W_app[l][k][n-128]
// Bt2[l][128][128]: n<108 -> W_app[l][108+k][n]
// bb1[l][256] fp32: pool bias | app bias (at n-128)
__global__ void k_pack(const float* __restrict__ W_pool, const float* __restrict__ b_pool,
                       const float* __restrict__ W_app, const float* __restrict__ b_app,
                       _Float16* Bt1, _Float16* Bt2, float* bb1) {
    int r = blockIdx.x * 256 + threadIdx.x;
    if (r < NL * 256 * 128) {
        int l = r / (256 * 128); int t = r % (256 * 128); int n = t / 128, k = t % 128;
        float v = 0.f;
        if (k < HID) {
            if (n < HID)                        v = W_pool[((size_t)l * HID + k) * HID + n];
            else if (n >= 128 && n < 128 + HID) v = W_app[((size_t)l * 216 + k) * HID + (n - 128)];
        }
        Bt1[r] = (_Float16)v; return;
    } r -= NL * 256 * 128;
    if (r < NL * 128 * 128) {
        int l = r / (128 * 128); int t = r % (128 * 128); int n = t / 128, k = t % 128;
        float v = (n < HID && k < HID) ? W_app[((size_t)l * 216 + 108 + k) * HID + n] : 0.f;
        Bt2[r] = (_Float16)v; return;
    } r -= NL * 128 * 128;
    if (r < NL * 256) {
        int l = r / 256, n = r % 256;
        float v = 0.f;
        if (n < HID) v = b_pool[l * HID + n];
        else if (n >= 128 && n < 128 + HID) v = b_app[l * HID + (n - 128)];
        bb1[r] = v;
    }
}

// embed: h fp32 (stride 108) + h16 fp16 (stride 128, zero-padded cols)
__global__ void k_embed(const float* __restrict__ feat, const float* __restrict__ W,
                        const float* __restrict__ b,
                        float* __restrict__ h, _Float16* __restrict__ h16) {
    int i = blockIdx.x * 256 + threadIdx.x;
    if (i >= NN * 128) return;
    int n = i >> 7, c = i & 127;
    if (c < HID) {
        float acc = b[c];
        const float* fr = feat + (size_t)n * IND;
        for (int k = 0; k < IND; k++) acc += fr[k] * W[k * HID + c];
        h[(size_t)n * HID + c] = acc;
        h16[i] = (_Float16)acc;
    } else {
        h16[i] = (_Float16)0.f;
    }
}

// mm1: C[64,128] = A(h16)[64,128] @ Bt^T + bias. blockIdx.y selects N-tile:
// nt=0 -> hp16 = fp16(relu(C)); nt=1 -> part = C (fp32)
__global__ __launch_bounds__(256)
void k_mm1(const _Float16* __restrict__ A, const _Float16* __restrict__ Bt,
           const float* __restrict__ bias,
           _Float16* __restrict__ hp16, float* __restrict__ part) {
    __shared__ _Float16 Bl[128 * LDSK];
    int tid = threadIdx.x;
    int nt = blockIdx.y;
    const _Float16* Bsrc = Bt + (size_t)nt * 128 * 128;
    for (int i = tid; i < 128 * 16; i += 256) {
        int rr = i >> 4, g = i & 15;
        *(uint4*)&Bl[rr * LDSK + g * 8] = *(const uint4*)(Bsrc + rr * 128 + g * 8);
    }
    __syncthreads();
    int lane = tid & 63, wid = tid >> 6, lm = lane & 15, lq = lane >> 4;
    int m0 = blockIdx.x * 64;
    floatx4 acc[4][2];
    #pragma unroll
    for (int mi = 0; mi < 4; mi++)
        #pragma unroll
        for (int ni = 0; ni < 2; ni++) { floatx4 z = {0.f,0.f,0.f,0.f}; acc[mi][ni] = z; }
    f16x8 zf = {(_Float16)0, (_Float16)0, (_Float16)0, (_Float16)0,
                (_Float16)0, (_Float16)0, (_Float16)0, (_Float16)0};
    #pragma unroll
    for (int ks = 0; ks < 4; ks++) {
        f16x8 a[4], b[2];
        #pragma unroll
        for (int mi = 0; mi < 4; mi++) {
            int row = m0 + mi * 16 + lm;
            a[mi] = (row < NN) ? *(const f16x8*)(A + (size_t)row * 128 + ks * 32 + lq * 8) : zf;
        }
        #pragma unroll
        for (int ni = 0; ni < 2; ni++)
            b[ni] = *(const f16x8*)&Bl[(wid * 32 + ni * 16 + lm) * LDSK + ks * 32 + lq * 8];
        #pragma unroll
        for (int mi = 0; mi < 4; mi++)
            #pragma unroll
            for (int ni = 0; ni < 2; ni++)
                acc[mi][ni] = __builtin_amdgcn_mfma_f32_16x16x32_f16(a[mi], b[ni], acc[mi][ni], 0, 0, 0);
    }
    #pragma unroll
    for (int mi = 0; mi < 4; mi++)
        #pragma unroll
        for (int ni = 0; ni < 2; ni++) {
            int col = wid * 32 + ni * 16 + lm;
            float bc = bias[nt * 128 + col];
            #pragma unroll
            for (int r = 0; r < 4; r++) {
                int row = m0 + mi * 16 + lq * 4 + r;
                if (row < NN) {
                    float v = acc[mi][ni][r] + bc;
                    if (nt == 0) hp16[(size_t)row * 128 + col] = (_Float16)fmaxf(v, 0.f);
                    else         part[(size_t)row * 128 + col] = v;
                }
            }
        }
}

// agg16[n][:] = fp16(mean over in-neighbors of hp16). 128 thr: 8 edge-slices x 16 lanes x 8 cols.
__global__ __launch_bounds__(128)
void k_agg(const _Float16* __restrict__ hp16, const int* __restrict__ rp,
           const int* __restrict__ cs, _Float16* __restrict__ agg16) {
    __shared__ float asl[8][128];
    int n = blockIdx.x, tid = threadIdx.x;
    int t = tid & 15, q = tid >> 4;
    int s0 = rp[n], s1 = rp[n + 1];
    float a[8];
    #pragma unroll
    for (int j = 0; j < 8; j++) a[j] = 0.f;
    int co = t * 8;
    for (int e = s0 + q; e < s1; e += 8) {
        f16x8 v = *(const f16x8*)(hp16 + (size_t)cs[e] * 128 + co);
        #pragma unroll
        for (int j = 0; j < 8; j++) a[j] += (float)v[j];
    }
    #pragma unroll
    for (int j = 0; j < 8; j++) asl[q][co + j] = a[j];
    __syncthreads();
    int col = tid;
    float s = 0.f;
    #pragma unroll
    for (int qq = 0; qq < 8; qq++) s += asl[qq][col];
    int dg = s1 - s0;
    float inv = 1.0f / (float)((dg > 1) ? dg : 1);
    agg16[(size_t)n * 128 + col] = (_Float16)(s * inv);
}

// mm2: bu = agg16 @ Bt2^T + part; per-row l2norm -> relu -> h += ; write h fp32 + h16
__global__ __launch_bounds__(256)
void k_mm2(const _Float16* __restrict__ A, const _Float16* __restrict__ Bt,
           const float* __restrict__ part,
           float* __restrict__ h, _Float16* __restrict__ h16) {
    __shared__ _Float16 Bl[128 * LDSK];
    __shared__ float ssl[64 * 4];
    __shared__ float scl[64];
    int tid = threadIdx.x;
    for (int i = tid; i < 128 * 16; i += 256) {
        int rr = i >> 4, g = i & 15;
        *(uint4*)&Bl[rr * LDSK + g * 8] = *(const uint4*)(Bt + rr * 128 + g * 8);
    }
    __syncthreads();
    int lane = tid & 63, wid = tid >> 6, lm = lane & 15, lq = lane >> 4;
    int m0 = blockIdx.x * 64;
    floatx4 acc[4][2];
    #pragma unroll
    for (int mi = 0; mi < 4; mi++)
        #pragma unroll
        for (int ni = 0; ni < 2; ni++) { floatx4 z = {0.f,0.f,0.f,0.f}; acc[mi][ni] = z; }
    f16x8 zf = {(_Float16)0, (_Float16)0, (_Float16)0, (_Float16)0,
                (_Float16)0, (_Float16)0, (_Float16)0, (_Float16)0};
    #pragma unroll
    for (int ks = 0; ks < 4; ks++) {
        f16x8 a[4], b[2];
        #pragma unroll
        for (int mi = 0; mi < 4; mi++) {
            int row = m0 + mi * 16 + lm;
            a[mi] = (row < NN) ? *(const f16x8*)(A + (size_t)row * 128 + ks * 32 + lq * 8) : zf;
        }
        #pragma unroll
        for (int ni = 0; ni < 2; ni++)
            b[ni] = *(const f16x8*)&Bl[(wid * 32 + ni * 16 + lm) * LDSK + ks * 32 + lq * 8];
        #pragma unroll
        for (int mi = 0; mi < 4; mi++)
            #pragma unroll
            for (int ni = 0; ni < 2; ni++)
                acc[mi][ni] = __builtin_amdgcn_mfma_f32_16x16x32_f16(a[mi], b[ni], acc[mi][ni], 0, 0, 0);
    }
    // bu = acc + part; rows >= NN contribute 0
    #pragma unroll
    for (int mi = 0; mi < 4; mi++)
        #pragma unroll
        for (int ni = 0; ni < 2; ni++) {
            int col = wid * 32 + ni * 16 + lm;
            #pragma unroll
            for (int r = 0; r < 4; r++) {
                int row = m0 + mi * 16 + lq * 4 + r;
                acc[mi][ni][r] = (row < NN) ? acc[mi][ni][r] + part[(size_t)row * 128 + col] : 0.f;
            }
        }
    // per-row sum of squares: intra-wave over 16 col-lanes, then LDS across 4 waves
    float ss[4][4];
    #pragma unroll
    for (int mi = 0; mi < 4; mi++)
        #pragma unroll
        for (int r = 0; r < 4; r++)
            ss[mi][r] = acc[mi][0][r] * acc[mi][0][r] + acc[mi][1][r] * acc[mi][1][r];
    #pragma unroll
    for (int off = 1; off < 16; off <<= 1)
        #pragma unroll
        for (int mi = 0; mi < 4; mi++)
            #pragma unroll
            for (int r = 0; r < 4; r++)
                ss[mi][r] += __shfl_xor(ss[mi][r], off, 64);
    if (lm == 0) {
        #pragma unroll
        for (int mi = 0; mi < 4; mi++)
            #pragma unroll
            for (int r = 0; r < 4; r++)
                ssl[(mi * 16 + lq * 4 + r) * 4 + wid] = ss[mi][r];
    }
    __syncthreads();
    if (tid < 64) {
        float s = ssl[tid * 4] + ssl[tid * 4 + 1] + ssl[tid * 4 + 2] + ssl[tid * 4 + 3];
        scl[tid] = 1.0f / fmaxf(sqrtf(s), 1e-12f);
    }
    __syncthreads();
    #pragma unroll
    for (int mi = 0; mi < 4; mi++)
        #pragma unroll
        for (int ni = 0; ni < 2; ni++) {
            int col = wid * 32 + ni * 16 + lm;
            if (col < HID) {
                #pragma unroll
                for (int r = 0; r < 4; r++) {
                    int rl = mi * 16 + lq * 4 + r;
                    int row = m0 + rl;
                    if (row < NN) {
                        float v = fmaxf(acc[mi][ni][r] * scl[rl], 0.f);
                        float hn = h[(size_t)row * HID + col] + v;
                        h[(size_t)row * HID + col] = hn;
                        h16[(size_t)row * 128 + col] = (_Float16)hn;
                    }
                }
            }
        }
}

__global__ void k_readout(const float* h, const int* gid,
                          const float* W1, const float* b1,
                          const float* W2, const float* b2,
                          const float* W3, const float* b3,
                          float* out) {
    __shared__ float hg[HID];
    __shared__ float y1[54];
    __shared__ float y2[27];
    __shared__ int se[2];
    int g = blockIdx.x, tid = threadIdx.x;
    if (tid < 2) {
        int key = g + tid, lo = 0, hi = NN;
        while (lo < hi) {
            int mid = (lo + hi) >> 1;
            if (gid[mid] < key) lo = mid + 1; else hi = mid;
        }
        se[tid] = lo;
    }
    __syncthreads();
    int s = se[0], e = se[1];
    if (tid < HID) {
        float acc = 0.f;
        for (int n = s; n < e; n++) acc += h[(size_t)n * HID + tid];
        int cnt = e - s;
        hg[tid] = acc / (float)((cnt > 1) ? cnt : 1);
    }
    __syncthreads();
    if (tid < 54) {
        float a = b1[tid];
        for (int k = 0; k < HID; k++) a += hg[k] * W1[k * 54 + tid];
        y1[tid] = fmaxf(a, 0.f);
    }
    __syncthreads();
    if (tid < 27) {
        float a = b2[tid];
        for (int k = 0; k < 54; k++) a += y1[k] * W2[k * 27 + tid];
        y2[tid] = fmaxf(a, 0.f);
    }
    __syncthreads();
    if (tid < 10) {
        float a = b3[tid];
        for (int k = 0; k < 27; k++) a += y2[k] * W3[k * 10 + tid];
        out[g * 10 + tid] = a;
    }
}

extern "C" void kernel_launch(void* const* d_in, const int* in_sizes, int n_in,
                              void* d_out, int out_size, void* d_ws, size_t ws_size,
                              hipStream_t stream) {
    float* out = (float*)d_out;
    (void)in_sizes; (void)n_in; (void)ws_size; (void)out_size;

    const float* feat   = (const float*)d_in[0];
    const int*   src    = (const int*)d_in[4];
    const int*   dst    = (const int*)d_in[5];
    const int*   gid    = (const int*)d_in[6];
    const float* W_emb  = (const float*)d_in[7];
    const float* b_emb  = (const float*)d_in[8];
    const float* W_pool = (const float*)d_in[9];
    const float* b_pool = (const float*)d_in[10];
    const float* W_app  = (const float*)d_in[11];
    const float* b_app  = (const float*)d_in[12];
    const float* W1     = (const float*)d_in[13];
    const float* b1     = (const float*)d_in[14];
    const float* W2     = (const float*)d_in[15];
    const float* b2     = (const float*)d_in[16];
    const float* W3     = (const float*)d_in[17];
    const float* b3     = (const float*)d_in[18];

    char* ws = (char*)d_ws;
    size_t off = 0;
    auto take = [&](size_t bytes) { char* p = ws + off; off += (bytes + 255) & ~(size_t)255; return p; };
    float*     h     = (float*)take((size_t)NN * HID * 4);
    _Float16*  h16   = (_Float16*)take((size_t)NN * 128 * 2);
    _Float16*  hp16  = (_Float16*)take((size_t)NN * 128 * 2);
    _Float16*  agg16 = (_Float16*)take((size_t)NN * 128 * 2);
    float*     part  = (float*)take((size_t)NN * 128 * 4);
    int*       cs    = (int*)take((size_t)EE * 4);
    int*       deg   = (int*)take((size_t)NN * 4);
    int*       rp    = (int*)take((size_t)(NN + 1) * 4);
    _Float16*  Bt1   = (_Float16*)take((size_t)NL * 256 * 128 * 2);
    _Float16*  Bt2   = (_Float16*)take((size_t)NL * 128 * 128 * 2);
    float*     bb1   = (float*)take((size_t)NL * 256 * 4);

    hipLaunchKernelGGL(k_zero, dim3((NN + 255) / 256), dim3(256), 0, stream, deg);
    hipLaunchKernelGGL(k_hist, dim3((EE + 255) / 256), dim3(256), 0, stream, dst, deg);
    hipLaunchKernelGGL(k_scan, dim3(1), dim3(1024), 0, stream, deg, rp);
    hipLaunchKernelGGL(k_scatter, dim3((EE + 255) / 256), dim3(256), 0, stream,
                       src, dst, rp, deg, cs);

    const int PACK_TOTAL = NL * 256 * 128 + NL * 128 * 128 + NL * 256;
    hipLaunchKernelGGL(k_pack, dim3((PACK_TOTAL + 255) / 256), dim3(256), 0, stream,
                       W_pool, b_pool, W_app, b_app, Bt1, Bt2, bb1);

    hipLaunchKernelGGL(k_embed, dim3((NN * 128 + 255) / 256), dim3(256), 0, stream,
                       feat, W_emb, b_emb, h, h16);

    for (int l = 0; l < NL; l++) {
        hipLaunchKernelGGL(k_mm1, dim3(MB, 2), dim3(256), 0, stream,
                           h16, Bt1 + (size_t)l * 256 * 128, bb1 + (size_t)l * 256,
                           hp16, part);
        hipLaunchKernelGGL(k_agg, dim3(NN), dim3(128), 0, stream, hp16, rp, cs, agg16);
        hipLaunchKernelGGL(k_mm2, dim3(MB), dim3(256), 0, stream,
                           agg16, Bt2 + (size_t)l * 128 * 128, part, h, h16);
    }
    hipLaunchKernelGGL(k_readout, dim3(GG), dim3(128), 0, stream,
                       h, gid, W1, b1, W2, b2, W3, b3, out);
}